// Round 8
// baseline (39.303 us; speedup 1.0000x reference)
//
#include <hip/hip_runtime.h>

// InfluenceEncoder: B=4096, N=257, D=16, H=128.
// Kernel A: QUARTER-batch per wave (16384 waves) to shorten the per-wave
//   critical path and double wave-level parallelism vs half-batch.
//   Wave W: batch b=W>>2, quarter q=W&3 (64 agents = 2 m-tiles of 32).
//   32x32x16 f16 MFMA, 2 m-tiles x 4 col-tiles = 8 MFMA/wave.
//   Weights computed from A-tile regs (x,y at k=0,1; f6 at k=6) by lo-half
//   lanes -> wave-private LDS slice (barrier-free), broadcast back as w4.
//   relu-bias fold: relu(e+b)=max(e,-b)+b. f16 unnormalized partials +
//   partial wsum to d_ws.
//   amdgpu_waves_per_eu(5,8): allocator targets ~102 VGPR (liveness ~85,
//   zero spill risk - R5 lesson), runtime gets >=5 waves/EU.
// Kernel B: 2048 waves; job = (16-row batch tile, 16-col tile).
//   renorm+bias+relu+f16cvt fused into A-frag path; 4x mfma_f32_16x16x32_f16
//   over K=128 vs Wagg^T; += bagg; fp32 out.

typedef _Float16 half_t;
typedef half_t f16x8 __attribute__((ext_vector_type(8)));
typedef float f32x4 __attribute__((ext_vector_type(4)));
typedef float f32x16 __attribute__((ext_vector_type(16)));

__global__ __launch_bounds__(256)
__attribute__((amdgpu_waves_per_eu(5, 8)))
void agg_kernel(
    const float* __restrict__ x,     // [4096,257,16]
    const float* __restrict__ Wfc,   // [128,16]
    const float* __restrict__ bfc,   // [128]
    half_t* __restrict__ p_ws,       // [4096][4][128] f16 unnormalized partials
    float* __restrict__ s_ws)        // [4096][4] partial weight sums
{
    const int t    = threadIdx.x;
    const int lane = t & 63;
    const int wv   = t >> 6;
    const int W    = blockIdx.x * 4 + wv;   // 0..16383
    const int b    = W >> 2;
    const int q    = W & 3;
    const int lm   = lane & 31;   // row-in-tile (A) / col-in-tile (B,D)
    const int hi   = lane >> 5;   // k-octet

    __shared__ float wls[4][64];

    const float* xb = x + (size_t)b * (257 * 16);
    const int row0 = 1 + q * 64;

    // ---- A-tile loads: 2 tiles of 32 rows; lane -> row lm, k [hi*8,+8) ----
    float4 a0[2], a1[2];
    #pragma unroll
    for (int tm = 0; tm < 2; ++tm) {
        const float* rp = xb + (size_t)(row0 + tm * 32 + lm) * 16 + hi * 8;
        a0[tm] = *(const float4*)rp;
        a1[tm] = *(const float4*)(rp + 4);
    }

    // ---- B-frags: B[k=hi*8+j][col=ct*32+lm] = Wfc[ct*32+lm][hi*8+j] ----
    f16x8 bfr[4];
    float nb[4];   // -bias for relu-fold
    #pragma unroll
    for (int ct = 0; ct < 4; ++ct) {
        const float* wp = Wfc + (size_t)(ct * 32 + lm) * 16 + hi * 8;
        const float4 w0 = *(const float4*)wp;
        const float4 w1 = *(const float4*)(wp + 4);
        bfr[ct] = (f16x8){(half_t)w0.x, (half_t)w0.y, (half_t)w0.z, (half_t)w0.w,
                          (half_t)w1.x, (half_t)w1.y, (half_t)w1.z, (half_t)w1.w};
        nb[ct] = -bfc[ct * 32 + lm];
    }

    const float2 ego = *(const float2*)xb;

    // ---- weights from A regs (lo lanes hold k=0..7: x,y at 0,1; f6 at 6) ----
    float wsum = 0.f;
    if (hi == 0) {
        #pragma unroll
        for (int tm = 0; tm < 2; ++tm) {
            const float dx = a0[tm].x - ego.x;
            const float dy = a0[tm].y - ego.y;
            float w = 1.0f / (sqrtf(dx * dx + dy * dy) + 1.0f);
            if (a1[tm].z == 1.0f) w *= 5.0f;   // k=6
            wls[wv][tm * 32 + lm] = w;
            wsum += w;
        }
    }
    #pragma unroll
    for (int off = 32; off > 0; off >>= 1) wsum += __shfl_xor(wsum, off);

    // ---- cvt A to f16 frags ----
    f16x8 afr[2];
    #pragma unroll
    for (int tm = 0; tm < 2; ++tm)
        afr[tm] = (f16x8){(half_t)a0[tm].x, (half_t)a0[tm].y, (half_t)a0[tm].z, (half_t)a0[tm].w,
                          (half_t)a1[tm].x, (half_t)a1[tm].y, (half_t)a1[tm].z, (half_t)a1[tm].w};

    // ---- MFMA + fold-relu weighted row-agg ----
    // D layout: col=lane&31, row=(r&3)+8*(r>>2)+4*hi
    float pacc[4] = {0.f, 0.f, 0.f, 0.f};
    #pragma unroll
    for (int tm = 0; tm < 2; ++tm) {
        float4 w4[4];
        #pragma unroll
        for (int g = 0; g < 4; ++g)
            w4[g] = *(const float4*)(&wls[wv][tm * 32 + g * 8 + hi * 4]);
        #pragma unroll
        for (int ct = 0; ct < 4; ++ct) {
            f32x16 zc = {};
            const f32x16 d = __builtin_amdgcn_mfma_f32_32x32x16_f16(afr[tm], bfr[ct], zc, 0, 0, 0);
            #pragma unroll
            for (int r = 0; r < 16; ++r)
                pacc[ct] = fmaf(w4[r >> 2][r & 3], fmaxf(d[r], nb[ct]), pacc[ct]);
        }
    }

    // ---- combine k-octet halves, store f16 partials ----
    #pragma unroll
    for (int ct = 0; ct < 4; ++ct) pacc[ct] += __shfl_xor(pacc[ct], 32);
    if (hi == 0) {
        half_t* pp = p_ws + ((size_t)b * 4 + q) * 128;
        #pragma unroll
        for (int ct = 0; ct < 4; ++ct) pp[ct * 32 + lm] = (half_t)pacc[ct];
        if (lane == 0) s_ws[b * 4 + q] = wsum;
    }
}

__global__ __launch_bounds__(256)
__attribute__((amdgpu_waves_per_eu(4, 8)))
void out_kernel(
    const half_t* __restrict__ p_ws, // [4096][4][128] f16
    const float* __restrict__ s_ws,  // [4096][4]
    const float* __restrict__ bfc,   // [128]
    const float* __restrict__ Wagg,  // [128,128]
    const float* __restrict__ bagg,  // [128]
    float* __restrict__ out)         // [4096,128]
{
    const int t    = threadIdx.x;
    const int lane = t & 63;
    const int wv   = t >> 6;
    const int j    = blockIdx.x * 4 + wv;  // 0..2047
    const int mt   = j >> 3;               // batch tile (16 rows)
    const int ct   = j & 7;                // col tile (16 cols)
    const int lr   = lane & 15;
    const int lq   = lane >> 4;

    const int brow = mt * 16 + lr;
    const float4 s4 = *(const float4*)(s_ws + brow * 4);
    const float inv = 1.0f / (s4.x + s4.y + s4.z + s4.w + 1e-10f);

    const int col = ct * 16 + lr;
    const float bb = bagg[col];
    f32x4 acc = (f32x4){bb, bb, bb, bb};

    const half_t* pb  = p_ws + (size_t)brow * 512;
    const float* wrow = Wagg + (size_t)col * 128;

    #pragma unroll
    for (int kk = 0; kk < 4; ++kk) {
        const int k0 = kk * 32 + lq * 8;
        const f16x8 p0 = *(const f16x8*)(pb + k0);
        const f16x8 p1 = *(const f16x8*)(pb + 128 + k0);
        const f16x8 p2 = *(const f16x8*)(pb + 256 + k0);
        const f16x8 p3 = *(const f16x8*)(pb + 384 + k0);
        const float4 bf0 = *(const float4*)(bfc + k0);
        const float4 bf1 = *(const float4*)(bfc + k0 + 4);
        float e[8];
        #pragma unroll
        for (int i = 0; i < 8; ++i) {
            const float s = (float)p0[i] + (float)p1[i] + (float)p2[i] + (float)p3[i];
            const float bv = (i < 4) ? (&bf0.x)[i] : (&bf1.x)[i - 4];
            e[i] = fmaxf(fmaf(s, inv, bv), 0.f);
        }
        const f16x8 afr = (f16x8){(half_t)e[0], (half_t)e[1], (half_t)e[2], (half_t)e[3],
                                  (half_t)e[4], (half_t)e[5], (half_t)e[6], (half_t)e[7]};
        const float4 wg0 = *(const float4*)(wrow + k0);
        const float4 wg1 = *(const float4*)(wrow + k0 + 4);
        const f16x8 bfr = (f16x8){(half_t)wg0.x, (half_t)wg0.y, (half_t)wg0.z, (half_t)wg0.w,
                                  (half_t)wg1.x, (half_t)wg1.y, (half_t)wg1.z, (half_t)wg1.w};
        acc = __builtin_amdgcn_mfma_f32_16x16x32_f16(afr, bfr, acc, 0, 0, 0);
    }

    // D: col=lane&15, row=lq*4+jj
    #pragma unroll
    for (int jj = 0; jj < 4; ++jj)
        out[(size_t)(mt * 16 + lq * 4 + jj) * 128 + col] = acc[jj];
}

extern "C" void kernel_launch(void* const* d_in, const int* in_sizes, int n_in,
                              void* d_out, int out_size, void* d_ws, size_t ws_size,
                              hipStream_t stream) {
    const float* x    = (const float*)d_in[0];
    const float* Wfc  = (const float*)d_in[1];
    const float* bfc  = (const float*)d_in[2];
    const float* Wagg = (const float*)d_in[3];
    const float* bagg = (const float*)d_in[4];
    float* out = (float*)d_out;

    half_t* p_ws = (half_t*)d_ws;                           // 4096*512 f16 = 4 MB
    float*  s_ws = (float*)((char*)d_ws + (size_t)4096 * 512 * sizeof(half_t));

    agg_kernel<<<dim3(4096), dim3(256), 0, stream>>>(x, Wfc, bfc, p_ws, s_ws);
    out_kernel<<<dim3(512), dim3(256), 0, stream>>>(p_ws, s_ws, bfc, Wagg, bagg, out);
}

// Round 9
// 31.693 us; speedup vs baseline: 1.2401x; 1.2401x over previous
//
#include <hip/hip_runtime.h>

// InfluenceEncoder: B=4096, N=257, D=16, H=128.
// Kernel A: QUARTER-batch per wave (16384 waves). 32x32x16 f16 MFMA.
//   Wave W: batch b=W>>2, quarter q=W&3 (64 agents = 2 m-tiles of 32).
//   Weights computed from A-tile regs (x,y at k=0,1; f6 at k=6) by lo-half
//   lanes -> wave-private LDS slice (barrier-free), broadcast back as w4.
//   relu-bias fold: relu(e+b)=max(e,-b)+b. f16 unnormalized partials +
//   partial wsum to d_ws.
//   REGISTER RULE (R5/R7 lessons): ONLY min=max amdgpu_waves_per_eu pins an
//   honest budget. (5,8) made the backend target 8 waves/EU -> 48 VGPRs ->
//   ~19 MB scratch spill per dispatch. (6,6) targets 85 VGPR; liveness ~80.
// Kernel B: 2048 waves; job = (16-row batch tile, 16-col tile).
//   renorm+bias+relu+f16cvt fused into A-frag path; 4x mfma_f32_16x16x32_f16
//   over K=128 vs Wagg^T; += bagg; fp32 out.

typedef _Float16 half_t;
typedef half_t f16x8 __attribute__((ext_vector_type(8)));
typedef float f32x4 __attribute__((ext_vector_type(4)));
typedef float f32x16 __attribute__((ext_vector_type(16)));

__global__ __launch_bounds__(256)
__attribute__((amdgpu_waves_per_eu(6, 6)))
void agg_kernel(
    const float* __restrict__ x,     // [4096,257,16]
    const float* __restrict__ Wfc,   // [128,16]
    const float* __restrict__ bfc,   // [128]
    half_t* __restrict__ p_ws,       // [4096][4][128] f16 unnormalized partials
    float* __restrict__ s_ws)        // [4096][4] partial weight sums
{
    const int t    = threadIdx.x;
    const int lane = t & 63;
    const int wv   = t >> 6;
    const int W    = blockIdx.x * 4 + wv;   // 0..16383
    const int b    = W >> 2;
    const int q    = W & 3;
    const int lm   = lane & 31;   // row-in-tile (A) / col-in-tile (B,D)
    const int hi   = lane >> 5;   // k-octet

    __shared__ float wls[4][64];

    const float* xb = x + (size_t)b * (257 * 16);
    const int row0 = 1 + q * 64;

    // ---- A-tile loads: 2 tiles of 32 rows; lane -> row lm, k [hi*8,+8) ----
    float4 a0[2], a1[2];
    #pragma unroll
    for (int tm = 0; tm < 2; ++tm) {
        const float* rp = xb + (size_t)(row0 + tm * 32 + lm) * 16 + hi * 8;
        a0[tm] = *(const float4*)rp;
        a1[tm] = *(const float4*)(rp + 4);
    }

    // ---- B-frags: B[k=hi*8+j][col=ct*32+lm] = Wfc[ct*32+lm][hi*8+j] ----
    f16x8 bfr[4];
    float nb[4];   // -bias for relu-fold
    #pragma unroll
    for (int ct = 0; ct < 4; ++ct) {
        const float* wp = Wfc + (size_t)(ct * 32 + lm) * 16 + hi * 8;
        const float4 w0 = *(const float4*)wp;
        const float4 w1 = *(const float4*)(wp + 4);
        bfr[ct] = (f16x8){(half_t)w0.x, (half_t)w0.y, (half_t)w0.z, (half_t)w0.w,
                          (half_t)w1.x, (half_t)w1.y, (half_t)w1.z, (half_t)w1.w};
        nb[ct] = -bfc[ct * 32 + lm];
    }

    const float2 ego = *(const float2*)xb;

    // ---- weights from A regs (lo lanes hold k=0..7: x,y at 0,1; f6 at 6) ----
    float wsum = 0.f;
    if (hi == 0) {
        #pragma unroll
        for (int tm = 0; tm < 2; ++tm) {
            const float dx = a0[tm].x - ego.x;
            const float dy = a0[tm].y - ego.y;
            float w = 1.0f / (sqrtf(dx * dx + dy * dy) + 1.0f);
            if (a1[tm].z == 1.0f) w *= 5.0f;   // k=6
            wls[wv][tm * 32 + lm] = w;
            wsum += w;
        }
    }
    #pragma unroll
    for (int off = 32; off > 0; off >>= 1) wsum += __shfl_xor(wsum, off);

    // ---- cvt A to f16 frags ----
    f16x8 afr[2];
    #pragma unroll
    for (int tm = 0; tm < 2; ++tm)
        afr[tm] = (f16x8){(half_t)a0[tm].x, (half_t)a0[tm].y, (half_t)a0[tm].z, (half_t)a0[tm].w,
                          (half_t)a1[tm].x, (half_t)a1[tm].y, (half_t)a1[tm].z, (half_t)a1[tm].w};

    // ---- MFMA + fold-relu weighted row-agg ----
    // D layout: col=lane&31, row=(r&3)+8*(r>>2)+4*hi
    float pacc[4] = {0.f, 0.f, 0.f, 0.f};
    #pragma unroll
    for (int tm = 0; tm < 2; ++tm) {
        float4 w4[4];
        #pragma unroll
        for (int g = 0; g < 4; ++g)
            w4[g] = *(const float4*)(&wls[wv][tm * 32 + g * 8 + hi * 4]);
        #pragma unroll
        for (int ct = 0; ct < 4; ++ct) {
            f32x16 zc = {};
            const f32x16 d = __builtin_amdgcn_mfma_f32_32x32x16_f16(afr[tm], bfr[ct], zc, 0, 0, 0);
            #pragma unroll
            for (int r = 0; r < 16; ++r)
                pacc[ct] = fmaf(w4[r >> 2][r & 3], fmaxf(d[r], nb[ct]), pacc[ct]);
        }
    }

    // ---- combine k-octet halves, store f16 partials ----
    #pragma unroll
    for (int ct = 0; ct < 4; ++ct) pacc[ct] += __shfl_xor(pacc[ct], 32);
    if (hi == 0) {
        half_t* pp = p_ws + ((size_t)b * 4 + q) * 128;
        #pragma unroll
        for (int ct = 0; ct < 4; ++ct) pp[ct * 32 + lm] = (half_t)pacc[ct];
        if (lane == 0) s_ws[b * 4 + q] = wsum;
    }
}

__global__ __launch_bounds__(256)
__attribute__((amdgpu_waves_per_eu(6, 6)))
void out_kernel(
    const half_t* __restrict__ p_ws, // [4096][4][128] f16
    const float* __restrict__ s_ws,  // [4096][4]
    const float* __restrict__ bfc,   // [128]
    const float* __restrict__ Wagg,  // [128,128]
    const float* __restrict__ bagg,  // [128]
    float* __restrict__ out)         // [4096,128]
{
    const int t    = threadIdx.x;
    const int lane = t & 63;
    const int wv   = t >> 6;
    const int j    = blockIdx.x * 4 + wv;  // 0..2047
    const int mt   = j >> 3;               // batch tile (16 rows)
    const int ct   = j & 7;                // col tile (16 cols)
    const int lr   = lane & 15;
    const int lq   = lane >> 4;

    const int brow = mt * 16 + lr;
    const float4 s4 = *(const float4*)(s_ws + brow * 4);
    const float inv = 1.0f / (s4.x + s4.y + s4.z + s4.w + 1e-10f);

    const int col = ct * 16 + lr;
    const float bb = bagg[col];
    f32x4 acc = (f32x4){bb, bb, bb, bb};

    const half_t* pb  = p_ws + (size_t)brow * 512;
    const float* wrow = Wagg + (size_t)col * 128;

    #pragma unroll
    for (int kk = 0; kk < 4; ++kk) {
        const int k0 = kk * 32 + lq * 8;
        const f16x8 p0 = *(const f16x8*)(pb + k0);
        const f16x8 p1 = *(const f16x8*)(pb + 128 + k0);
        const f16x8 p2 = *(const f16x8*)(pb + 256 + k0);
        const f16x8 p3 = *(const f16x8*)(pb + 384 + k0);
        const float4 bf0 = *(const float4*)(bfc + k0);
        const float4 bf1 = *(const float4*)(bfc + k0 + 4);
        float e[8];
        #pragma unroll
        for (int i = 0; i < 8; ++i) {
            const float s = (float)p0[i] + (float)p1[i] + (float)p2[i] + (float)p3[i];
            const float bv = (i < 4) ? (&bf0.x)[i] : (&bf1.x)[i - 4];
            e[i] = fmaxf(fmaf(s, inv, bv), 0.f);
        }
        const f16x8 afr = (f16x8){(half_t)e[0], (half_t)e[1], (half_t)e[2], (half_t)e[3],
                                  (half_t)e[4], (half_t)e[5], (half_t)e[6], (half_t)e[7]};
        const float4 wg0 = *(const float4*)(wrow + k0);
        const float4 wg1 = *(const float4*)(wrow + k0 + 4);
        const f16x8 bfr = (f16x8){(half_t)wg0.x, (half_t)wg0.y, (half_t)wg0.z, (half_t)wg0.w,
                                  (half_t)wg1.x, (half_t)wg1.y, (half_t)wg1.z, (half_t)wg1.w};
        acc = __builtin_amdgcn_mfma_f32_16x16x32_f16(afr, bfr, acc, 0, 0, 0);
    }

    // D: col=lane&15, row=lq*4+jj
    #pragma unroll
    for (int jj = 0; jj < 4; ++jj)
        out[(size_t)(mt * 16 + lq * 4 + jj) * 128 + col] = acc[jj];
}

extern "C" void kernel_launch(void* const* d_in, const int* in_sizes, int n_in,
                              void* d_out, int out_size, void* d_ws, size_t ws_size,
                              hipStream_t stream) {
    const float* x    = (const float*)d_in[0];
    const float* Wfc  = (const float*)d_in[1];
    const float* bfc  = (const float*)d_in[2];
    const float* Wagg = (const float*)d_in[3];
    const float* bagg = (const float*)d_in[4];
    float* out = (float*)d_out;

    half_t* p_ws = (half_t*)d_ws;                           // 4096*512 f16 = 4 MB
    float*  s_ws = (float*)((char*)d_ws + (size_t)4096 * 512 * sizeof(half_t));

    agg_kernel<<<dim3(4096), dim3(256), 0, stream>>>(x, Wfc, bfc, p_ws, s_ws);
    out_kernel<<<dim3(512), dim3(256), 0, stream>>>(p_ws, s_ws, bfc, Wagg, bagg, out);
}